// Round 2
// baseline (38.190 us; speedup 1.0000x reference)
//
#include <hip/hip_runtime.h>

// GriddingReverse: grid (B=32, 64^3) f32 -> ptcloud (B, 64^3, 3) f32.
// 4 voxels (consecutive x) per thread:
//   loads:  4 rows x (float4 + 1 scalar)  (8 corner values of 4 cells = 4x5 row window)
//   math:   shared column sums  wsum(x)=s[x-1]+s[x], wx1(x)=s[x],
//           wy1(x)=u[x-1]+u[x] (u=rB+rD), wz1(x)=v[x-1]+v[x] (v=rC+rD)
//   stores: 3x float4, fully coalesced (48 B/lane contiguous)

__global__ __launch_bounds__(256)
void GriddingReverse_kernel(const float* __restrict__ grid,
                            float* __restrict__ out,
                            int nthreads)
{
    int tid = blockIdx.x * blockDim.x + threadIdx.x;
    if (tid >= nthreads) return;

    int idx0 = tid << 2;             // first of 4 voxel indices
    int x0 = idx0 & 63;              // multiple of 4
    int y  = (idx0 >> 6) & 63;
    int z  = (idx0 >> 12) & 63;
    int b  = idx0 >> 18;

    float px[4] = {0.f, 0.f, 0.f, 0.f};
    float py[4] = {0.f, 0.f, 0.f, 0.f};
    float pz[4] = {0.f, 0.f, 0.f, 0.f};

    if (y > 0 && z > 0) {
        const float* __restrict__ g = grid + ((size_t)b << 18);
        int rA = ((z - 1) << 12) + ((y - 1) << 6);  // (z-1, y-1)
        int rB = rA + 64;                           // (z-1, y  )
        int rC = rA + 4096;                         // (z,   y-1)
        int rD = rC + 64;                           // (z,   y  )

        float4 qA = *reinterpret_cast<const float4*>(g + rA + x0);
        float4 qB = *reinterpret_cast<const float4*>(g + rB + x0);
        float4 qC = *reinterpret_cast<const float4*>(g + rC + x0);
        float4 qD = *reinterpret_cast<const float4*>(g + rD + x0);
        float mA = 0.f, mB = 0.f, mC = 0.f, mD = 0.f;
        if (x0 > 0) {                                // left-neighbor column
            mA = g[rA + x0 - 1];
            mB = g[rB + x0 - 1];
            mC = g[rC + x0 - 1];
            mD = g[rD + x0 - 1];
        }

        float aV[5] = {mA, qA.x, qA.y, qA.z, qA.w};
        float bV[5] = {mB, qB.x, qB.y, qB.z, qB.w};
        float cV[5] = {mC, qC.x, qC.y, qC.z, qC.w};
        float dV[5] = {mD, qD.x, qD.y, qD.z, qD.w};

        float s[5], u[5], v[5];
        #pragma unroll
        for (int k = 0; k < 5; ++k) {
            u[k] = bV[k] + dV[k];               // wy1 contribution
            v[k] = cV[k] + dV[k];               // wz1 contribution
            s[k] = (aV[k] + bV[k]) + v[k];      // full column sum (a+b+c+d)
        }

        const float sc = 2.0f / 64.0f;
        float fy = (float)(y - 1) - 32.0f;
        float fz = (float)(z - 1) - 32.0f;
        #pragma unroll
        for (int i = 0; i < 4; ++i) {
            int x = x0 + i;
            if (x > 0) {
                float wsum = s[i] + s[i + 1];
                if (wsum > 0.0f) {
                    float inv = 1.0f / wsum;
                    px[i] = ((float)(x - 1) - 32.0f + s[i + 1] * inv) * sc;
                    py[i] = (fy + (u[i] + u[i + 1]) * inv) * sc;
                    pz[i] = (fz + (v[i] + v[i + 1]) * inv) * sc;
                }
            }
        }
    }

    float4* op = reinterpret_cast<float4*>(out + (size_t)idx0 * 3);  // 48B-aligned
    op[0] = make_float4(px[0], py[0], pz[0], px[1]);
    op[1] = make_float4(py[1], pz[1], px[2], py[2]);
    op[2] = make_float4(pz[2], px[3], py[3], pz[3]);
}

extern "C" void kernel_launch(void* const* d_in, const int* in_sizes, int n_in,
                              void* d_out, int out_size, void* d_ws, size_t ws_size,
                              hipStream_t stream)
{
    const float* grid = (const float*)d_in[0];
    float* out = (float*)d_out;
    int total = in_sizes[0];             // B * 64^3 = 8,388,608 voxels
    int nthreads = total >> 2;           // 4 voxels per thread
    int block = 256;
    int ngrid = (nthreads + block - 1) / block;
    GriddingReverse_kernel<<<ngrid, block, 0, stream>>>(grid, out, nthreads);
}

// Round 3
// 27.964 us; speedup vs baseline: 1.3657x; 1.3657x over previous
//
#include <hip/hip_runtime.h>

// GriddingReverse: grid (B=32, 64^3) f32 -> ptcloud (B, 64^3, 3) f32.
// 1 voxel/thread (R0 structure: perfectly coalesced 4B/lane loads, caches
// absorb the 8x corner reuse) + LDS-transposed stores: block of 256 voxels
// stages 768 output floats in LDS, then writes the contiguous 3072B span as
// 192 float4 stores (16B/lane, 1KB/instruction) instead of strided dwords.

#define DX 64
#define DY 64

__global__ __launch_bounds__(256)
void GriddingReverse_kernel(const float* __restrict__ grid,
                            float* __restrict__ out)
{
    __shared__ float sm[768];   // 256 voxels * 3 floats

    int t = threadIdx.x;
    int idx = blockIdx.x * 256 + t;

    int x = idx & 63;
    int y = (idx >> 6) & 63;
    int z = (idx >> 12) & 63;
    int b = idx >> 18;

    float ox = 0.0f, oy = 0.0f, oz = 0.0f;

    if (x > 0 && y > 0 && z > 0) {
        const float* __restrict__ g = grid + ((size_t)b << 18);
        int base = ((z - 1) << 12) + ((y - 1) << 6) + (x - 1);
        float c000 = g[base];
        float c001 = g[base + 1];
        float c010 = g[base + DX];
        float c011 = g[base + DX + 1];
        float c100 = g[base + DX * DY];
        float c101 = g[base + DX * DY + 1];
        float c110 = g[base + DX * DY + DX];
        float c111 = g[base + DX * DY + DX + 1];

        float v0 = c100 + c101;               // z=1 pair
        float v1 = c110 + c111;               // z=1,y=1 pair
        float wz1 = v0 + v1;
        float wy1 = (c010 + c011) + v1;
        float wx1 = (c001 + c011) + (c101 + c111);
        float wsum = ((c000 + c001) + (c010 + c011)) + wz1;

        if (wsum > 0.0f) {
            float inv = 1.0f / wsum;
            const float s = 2.0f / 64.0f;
            ox = ((float)(x - 1) + wx1 * inv - 32.0f) * s;
            oy = ((float)(y - 1) + wy1 * inv - 32.0f) * s;
            oz = ((float)(z - 1) + wz1 * inv - 32.0f) * s;
        }
    }

    sm[t * 3 + 0] = ox;          // lane stride 3 dwords: 2-way bank alias, free
    sm[t * 3 + 1] = oy;
    sm[t * 3 + 2] = oz;
    __syncthreads();

    // Block's output span: 768 floats = 3072B, 16B-aligned, contiguous.
    if (t < 192) {
        const float4* s4 = reinterpret_cast<const float4*>(sm);
        float4* o4 = reinterpret_cast<float4*>(out + (size_t)blockIdx.x * 768);
        o4[t] = s4[t];
    }
}

extern "C" void kernel_launch(void* const* d_in, const int* in_sizes, int n_in,
                              void* d_out, int out_size, void* d_ws, size_t ws_size,
                              hipStream_t stream)
{
    const float* grid = (const float*)d_in[0];
    float* out = (float*)d_out;
    int total = in_sizes[0];            // B * 64^3 = 8,388,608 voxels
    int ngrid = total / 256;            // exact: 32768 blocks
    GriddingReverse_kernel<<<ngrid, 256, 0, stream>>>(grid, out);
}

// Round 4
// 26.311 us; speedup vs baseline: 1.4515x; 1.0628x over previous
//
#include <hip/hip_runtime.h>

// GriddingReverse: grid (B=32, 64^3) f32 -> ptcloud (B, 64^3, 3) f32.
// Wave = one x-row (64 lanes). Each lane loads only its OWN column's 4 corner
// rows (a,b,c,d), builds partial sums s=a+b+c+d, u=b+d, v=c+d, and obtains the
// x-1 column's sums from the neighboring lane via __shfl_up — 4 global loads
// instead of 8, zero redundant L1 traffic. y==0/z==0 waves are uniform (no
// loads). Stores staged in LDS, written as contiguous float4 (1KB/instr).

__global__ __launch_bounds__(256)
void GriddingReverse_kernel(const float* __restrict__ grid,
                            float* __restrict__ out)
{
    __shared__ float sm[768];   // 256 voxels * 3 floats

    int t = threadIdx.x;
    int idx = blockIdx.x * 256 + t;

    int x = idx & 63;
    int y = (idx >> 6) & 63;
    int z = (idx >> 12) & 63;
    int b = idx >> 18;

    float ox = 0.0f, oy = 0.0f, oz = 0.0f;

    if (y > 0 && z > 0) {                       // wave-uniform branch
        const float* __restrict__ g = grid + ((size_t)b << 18);
        int col = ((z - 1) << 12) + ((y - 1) << 6) + x;
        float a  = g[col];                      // (z-1, y-1, x)
        float bv = g[col + 64];                 // (z-1, y,   x)
        float c  = g[col + 4096];               // (z,   y-1, x)
        float d  = g[col + 4096 + 64];          // (z,   y,   x)

        float vv = c + d;                       // wz1 column part
        float uu = bv + d;                      // wy1 column part
        float ss = (a + bv) + vv;               // full column sum

        float sp = __shfl_up(ss, 1, 64);        // x-1 column from lane-1
        float up = __shfl_up(uu, 1, 64);
        float vp = __shfl_up(vv, 1, 64);

        if (x > 0) {
            float wsum = sp + ss;
            if (wsum > 0.0f) {
                float inv = 1.0f / wsum;
                const float s = 2.0f / 64.0f;
                ox = ((float)(x - 1) - 32.0f + ss * inv) * s;        // wx1 = ss
                oy = ((float)(y - 1) - 32.0f + (up + uu) * inv) * s; // wy1
                oz = ((float)(z - 1) - 32.0f + (vp + vv) * inv) * s; // wz1
            }
        }
    }

    sm[t * 3 + 0] = ox;
    sm[t * 3 + 1] = oy;
    sm[t * 3 + 2] = oz;
    __syncthreads();

    // Block's output span: 768 floats = 3072B, contiguous, 16B-aligned.
    if (t < 192) {
        const float4* s4 = reinterpret_cast<const float4*>(sm);
        float4* o4 = reinterpret_cast<float4*>(out + (size_t)blockIdx.x * 768);
        o4[t] = s4[t];
    }
}

extern "C" void kernel_launch(void* const* d_in, const int* in_sizes, int n_in,
                              void* d_out, int out_size, void* d_ws, size_t ws_size,
                              hipStream_t stream)
{
    const float* grid = (const float*)d_in[0];
    float* out = (float*)d_out;
    int total = in_sizes[0];            // B * 64^3 = 8,388,608 voxels
    int ngrid = total / 256;            // exact: 32768 blocks
    GriddingReverse_kernel<<<ngrid, 256, 0, stream>>>(grid, out);
}